// Round 1
// baseline (702.801 us; speedup 1.0000x reference)
//
#include <hip/hip_runtime.h>

#define B_ 4096
#define L_ 200
#define D_ 128

__global__ __launch_bounds__(256, 8) void tahe_kernel(
    const float* __restrict__ rec,     // [B,L,D] recentTimeRepresentations
    const float* __restrict__ cur,     // [B,D]   curTimeRepresentation
    const int*   __restrict__ ts,      // [B,L]   recentTimestamps
    const float* __restrict__ item,    // [B,L,D] recentItemEmbeddings
    float*       __restrict__ out)     // [B,D]   userHistoryRepresentation
{
    const int b   = blockIdx.x;
    const int tid = threadIdx.x;

    __shared__ int    s_act[L_];   // compacted active l indices
    __shared__ int    s_n;
    __shared__ float4 s_red[8][32];

    if (tid == 0) s_n = 0;
    __syncthreads();

    // Compact active (mask==1) indices; ~50% masked -> skip those rows' 1KB
    // of HBM traffic entirely. Order nondeterminism only reorders an fp sum.
    if (tid < L_) {
        if (ts[b * L_ + tid] > 0) {
            int p = atomicAdd(&s_n, 1);
            s_act[p] = tid;
        }
    }

    const int hw  = tid >> 5;   // half-wave id 0..7 (one row per half-wave)
    const int sub = tid & 31;   // lane within half-wave: owns float4 chunk `sub`

    // ||cur||^-1 per half-wave, fully in registers: butterfly reduce leaves
    // the sum in EVERY lane -> no LDS, no broadcast, overlaps the barrier.
    const float4 c4 = *(const float4*)(cur + (size_t)b * D_ + sub * 4);
    float css = fmaf(c4.x, c4.x, fmaf(c4.y, c4.y, fmaf(c4.z, c4.z, c4.w * c4.w)));
    #pragma unroll
    for (int m = 1; m <= 16; m <<= 1) css += __shfl_xor(css, m);
    float cinv = rsqrtf(fmaxf(css, 1e-12f));
    cinv = cinv * (1.5f - 0.5f * css * cinv * cinv);   // NR step for fp32 accuracy

    __syncthreads();
    const int n = s_n;

    const float* recb  = rec  + (size_t)b * (L_ * D_);
    const float* itemb = item + (size_t)b * (L_ * D_);

    // Fused similarity + pooling: each half-wave streams rows i = hw, hw+8,...
    // (same per-element summation order as the old Phase B). 2x unroll keeps
    // 4 independent 512B streams (2 rec + 2 item) in flight per iteration.
    float4 acc = make_float4(0.f, 0.f, 0.f, 0.f);

    int i = hw;
    for (; i + 8 < n; i += 16) {
        const int l0 = s_act[i];
        const int l1 = s_act[i + 8];
        const float4 r0 = *(const float4*)(recb  + (size_t)l0 * D_ + sub * 4);
        const float4 t0 = *(const float4*)(itemb + (size_t)l0 * D_ + sub * 4);
        const float4 r1 = *(const float4*)(recb  + (size_t)l1 * D_ + sub * 4);
        const float4 t1 = *(const float4*)(itemb + (size_t)l1 * D_ + sub * 4);

        float pd0 = fmaf(c4.x, r0.x, fmaf(c4.y, r0.y, fmaf(c4.z, r0.z, c4.w * r0.w)));
        float ps0 = fmaf(r0.x, r0.x, fmaf(r0.y, r0.y, fmaf(r0.z, r0.z, r0.w * r0.w)));
        float pd1 = fmaf(c4.x, r1.x, fmaf(c4.y, r1.y, fmaf(c4.z, r1.z, c4.w * r1.w)));
        float ps1 = fmaf(r1.x, r1.x, fmaf(r1.y, r1.y, fmaf(r1.z, r1.z, r1.w * r1.w)));

        #pragma unroll
        for (int m = 1; m <= 16; m <<= 1) {
            pd0 += __shfl_xor(pd0, m);
            ps0 += __shfl_xor(ps0, m);
            pd1 += __shfl_xor(pd1, m);
            ps1 += __shfl_xor(ps1, m);
        }

        float rs0 = rsqrtf(fmaxf(ps0, 1e-12f));
        rs0 = rs0 * (1.5f - 0.5f * ps0 * rs0 * rs0);
        float rs1 = rsqrtf(fmaxf(ps1, 1e-12f));
        rs1 = rs1 * (1.5f - 0.5f * ps1 * rs1 * rs1);
        const float w0 = fmaf(pd0 * rs0 * cinv, 0.5f, 0.5f);  // mask==1 here
        const float w1 = fmaf(pd1 * rs1 * cinv, 0.5f, 0.5f);

        // acc + w0*t0 + w1*t1 in that order (matches sequential i order)
        acc.x = fmaf(w1, t1.x, fmaf(w0, t0.x, acc.x));
        acc.y = fmaf(w1, t1.y, fmaf(w0, t0.y, acc.y));
        acc.z = fmaf(w1, t1.z, fmaf(w0, t0.z, acc.z));
        acc.w = fmaf(w1, t1.w, fmaf(w0, t0.w, acc.w));
    }
    if (i < n) {   // tail row
        const int l0 = s_act[i];
        const float4 r0 = *(const float4*)(recb  + (size_t)l0 * D_ + sub * 4);
        const float4 t0 = *(const float4*)(itemb + (size_t)l0 * D_ + sub * 4);
        float pd0 = fmaf(c4.x, r0.x, fmaf(c4.y, r0.y, fmaf(c4.z, r0.z, c4.w * r0.w)));
        float ps0 = fmaf(r0.x, r0.x, fmaf(r0.y, r0.y, fmaf(r0.z, r0.z, r0.w * r0.w)));
        #pragma unroll
        for (int m = 1; m <= 16; m <<= 1) {
            pd0 += __shfl_xor(pd0, m);
            ps0 += __shfl_xor(ps0, m);
        }
        float rs0 = rsqrtf(fmaxf(ps0, 1e-12f));
        rs0 = rs0 * (1.5f - 0.5f * ps0 * rs0 * rs0);
        const float w0 = fmaf(pd0 * rs0 * cinv, 0.5f, 0.5f);
        acc.x = fmaf(w0, t0.x, acc.x);
        acc.y = fmaf(w0, t0.y, acc.y);
        acc.z = fmaf(w0, t0.z, acc.z);
        acc.w = fmaf(w0, t0.w, acc.w);
    }

    s_red[hw][sub] = acc;
    __syncthreads();

    // Cross-half-wave combine + coalesced 512B store (conflict-free LDS reads).
    if (tid < D_) {
        const int chunk = tid >> 2, comp = tid & 3;
        float v = 0.f;
        #pragma unroll
        for (int gg = 0; gg < 8; ++gg) {
            const float* rf = (const float*)&s_red[gg][chunk];
            v += rf[comp];
        }
        out[(size_t)b * D_ + tid] = v;
    }
}

extern "C" void kernel_launch(void* const* d_in, const int* in_sizes, int n_in,
                              void* d_out, int out_size, void* d_ws, size_t ws_size,
                              hipStream_t stream) {
    const float* rec  = (const float*)d_in[0];
    const float* cur  = (const float*)d_in[1];
    const int*   ts   = (const int*)d_in[2];
    const float* item = (const float*)d_in[3];
    float*       out  = (float*)d_out;
    tahe_kernel<<<B_, 256, 0, stream>>>(rec, cur, ts, item, out);
}